// Round 5
// baseline (185.411 us; speedup 1.0000x reference)
//
#include <hip/hip_runtime.h>
#include <math.h>

// MHSA_27582279975470 — bf16/fp16 MFMA pipeline for MI355X (gfx950)
// B=4, C=256, NH=8, HD=32, H=W=64 -> Nq=4096, SR=2 -> Mkv=1024
//
// R16: k_attn issue-count halved via k=32 fp16 PV MFMA.
//  - Decomposition (R0-R15 data): ~93us of every measurement is two 256MB
//    harness fills in the timed stream; prep/xT/gemm_kv ~10us total (near
//    roofline); k_attn ~45us vs ~12us pipe floor (no pipe >35% busy).
//  - PV/rowsum: mfma_f32_16x16x32_f16 (gfx950 2xK) -> 12 MFMA/chunk (was
//    24), V reads 8x b128 (was 16x b64), accO chains halved.
//  - K staged with PERMUTED phys rows (j<16: kv=(j>>2)*8+(j&3); j>=16: +4)
//    so the two QK MFMAs per 32-kv block emit s0/s1 already in the k=32
//    A-frag layout (kv = 32kb + lg*8 + e) — no cross-lane ops. Read pattern
//    and koff swizzle identical (rows = lr / 16+lr mod 32); write rotation
//    keyed on permuted row. accO/accS/epilogue layouts unchanged.
//  - fp16 P/V kept -> precision identical (absmax should stay 0.0234375).
// k_prep_w / k_xT / k_gemm_kv byte-identical to R15.

typedef __bf16 bf16;
typedef __attribute__((ext_vector_type(4))) __bf16 bf16x4;
typedef __attribute__((ext_vector_type(8))) __bf16 bf16x8;
typedef __attribute__((ext_vector_type(4))) float f32x4;
typedef __attribute__((ext_vector_type(2))) __fp16 fp16x2_raw;   // cvt_pkrtz ret type
typedef __attribute__((ext_vector_type(4))) _Float16 f16x4;
typedef __attribute__((ext_vector_type(8))) _Float16 f16x8;

#define MFMA16 __builtin_amdgcn_mfma_f32_16x16x32_bf16      // D[row=A-row][col=B-row]
#define MFMA16H32 __builtin_amdgcn_mfma_f32_16x16x32_f16    // k=32, fp16 in (gfx950)

#define QSCALE 0.25503486f   // (1/sqrt(32)) * log2(e)
#define SOFTMAX_SHIFT 10.0f  // constant exp2-domain shift (softmax-invariant)
#define VSTR 140             // Vs row stride in f16 (dword stride 70 = 6 mod 32)

// ---------------------------------------------------------------- prep weights
__global__ void k_prep_w(const float* __restrict__ Wq, const float* __restrict__ Wk,
                         const float* __restrict__ Wv,
                         bf16* __restrict__ Wq_bf, bf16* __restrict__ Wkv_bf) {
    int tid = blockIdx.x * 256 + threadIdx.x;          // 0..49151
    if (tid < 32768) {
        // Wkv: thread handles (c, i4): 4 rows i, all 4 taps
        int c = tid >> 6, i4 = (tid & 63) * 4;         // c: 0..511 (k then v)
        const float* Wsrc = (c < 256) ? Wk : Wv;
        int cs = c & 255;
        f32x4 r[4];
#pragma unroll
        for (int j = 0; j < 4; j++)
            r[j] = ((const f32x4*)Wsrc)[cs * 256 + i4 + j];   // W[cs][i4+j][0..3]
#pragma unroll
        for (int tap = 0; tap < 4; tap++) {            // K-order: tap*256 + i
            bf16x4 o;
#pragma unroll
            for (int j = 0; j < 4; j++) o[j] = (bf16)r[j][tap];
            *(bf16x4*)(Wkv_bf + c * 1024 + tap * 256 + i4) = o;
        }
    } else {
        int q = tid - 32768;                           // 0..16383
        f32x4 q4 = ((const f32x4*)Wq)[q];
        bf16x4 o;
#pragma unroll
        for (int e = 0; e < 4; e++) o[e] = (bf16)(q4[e] * QSCALE);
        *(bf16x4*)(Wq_bf + q * 4) = o;                 // fold scale*log2e into q
    }
}

// ---------------------------------------------------------------- x transpose
__global__ void k_xT(const float* __restrict__ x, bf16* __restrict__ xT) {
    // grid (64 n-tiles, 4 c-tiles, 4 b), 256 thr, 64x64 tile
    int b = blockIdx.z, c0 = blockIdx.y * 64, n0 = blockIdx.x * 64;
    __shared__ float tile[64][65];                     // stride 65: bank-rotating
    int t = threadIdx.x;
    const float* xp = x + (size_t)(b * 256 + c0) * 4096 + n0;
    // load: 64 c-rows x 16 float4; 4 units/thread
#pragma unroll
    for (int it = 0; it < 4; it++) {
        int u = it * 256 + t;
        int row = u >> 4, colq = u & 15;               // row = c-local
        f32x4 v = *(const f32x4*)(xp + (size_t)row * 4096 + colq * 4);
#pragma unroll
        for (int e = 0; e < 4; e++) tile[row][colq * 4 + e] = v[e];
    }
    __syncthreads();
    bf16* op = xT + (size_t)(b * 4096 + n0) * 256 + c0;
    // store: 64 n-rows x 8 groups of 8 c; 2 units/thread, 16B stores
#pragma unroll
    for (int it = 0; it < 2; it++) {
        int u = it * 256 + t;
        int orow = u >> 3, oc8 = (u & 7) * 8;          // orow = n-local
        bf16x8 o;
#pragma unroll
        for (int e = 0; e < 8; e++) o[e] = (bf16)tile[oc8 + e][orow];
        *(bf16x8*)(op + (size_t)orow * 256 + oc8) = o;
    }
}

// ---------------------------------------------------------------- kv conv GEMM
// Block = 32 m x 64 c, computes BOTH kpos and v (P-frags shared between the
// two GEMMs). P rows staged in LDS (dbuf 2x16.5KB, reg-prefetch); each chunk
// = one tap (256 k). Weights read from global (1MB, L2-resident).
__launch_bounds__(256)
__global__ void k_gemm_kv(const bf16* __restrict__ xT, const bf16* __restrict__ Wkv_bf,
                          const float* __restrict__ rel_h, const float* __restrict__ rel_w,
                          bf16* __restrict__ kpos_t, _Float16* __restrict__ v_td) {
    int b = blockIdx.z;
    int bx = blockIdx.x;                               // m-tile: m0 = bx*32, y = bx
    int m0 = bx * 32;
    int c0w = blockIdx.y * 64 + (threadIdx.x >> 6) * 16;
    int t = threadIdx.x, l = t & 63;
    int lr = l & 15, lg = l >> 4;
    __shared__ __align__(16) bf16 Ps[2][32 * 264];     // row stride 264 (+8 pad)
    const bf16* xb = xT + (size_t)b * 4096 * 256;
    int srow = t >> 3;                                 // 4 units/thread: rows t>>3
    int scu0 = (t & 7) * 4;                            // cols (t&7)*4 .. +3
    uint4 pre[4];
#define LOAD_CHUNK(tap)                                                        \
    {                                                                          \
        int dy = (tap) >> 1, dx = (tap) & 1;                                   \
        const bf16* src = xb + (size_t)((2 * bx + dy) * 64 + 2 * srow + dx) * 256; \
        _Pragma("unroll")                                                      \
        for (int j = 0; j < 4; j++)                                            \
            pre[j] = *(const uint4*)(src + (scu0 + j) * 8);                    \
    }
#define WRITE_CHUNK(buf)                                                       \
    {                                                                          \
        bf16* dst = Ps[buf] + srow * 264 + scu0 * 8;                           \
        _Pragma("unroll")                                                      \
        for (int j = 0; j < 4; j++) *(uint4*)(dst + j * 8) = pre[j];           \
    }
    LOAD_CHUNK(0)
    WRITE_CHUNK(0)
    const bf16* Gkb = Wkv_bf + (size_t)(c0w + lr) * 1024 + lg * 8;
    const bf16* Gvb = Gkb + 256 * 1024;
    f32x4 accK[2] = {}, accV[2] = {};
    for (int ch = 0; ch < 4; ch++) {
        if (ch < 3) LOAD_CHUNK(ch + 1)
        __syncthreads();
        const bf16* P = Ps[ch & 1];
#pragma unroll
        for (int kk = 0; kk < 8; kk++) {
            bf16x8 pa0 = *(const bf16x8*)(P + lr * 264 + kk * 32 + lg * 8);
            bf16x8 pa1 = *(const bf16x8*)(P + (16 + lr) * 264 + kk * 32 + lg * 8);
            bf16x8 gk = *(const bf16x8*)(Gkb + ch * 256 + kk * 32);
            bf16x8 gv = *(const bf16x8*)(Gvb + ch * 256 + kk * 32);
            accK[0] = MFMA16(pa0, gk, accK[0], 0, 0, 0);
            accK[1] = MFMA16(pa1, gk, accK[1], 0, 0, 0);
            accV[0] = MFMA16(gv, pa0, accV[0], 0, 0, 0);
            accV[1] = MFMA16(gv, pa1, accV[1], 0, 0, 0);
        }
        if (ch < 3) {
            __syncthreads();
            WRITE_CHUNK((ch + 1) & 1)
        }
    }
    // kpos: accK[i] row m = m0+i*16+lg*4+r, col c = c0w+lr
    {
        int cc = c0w + lr;
        float rw = rel_w[cc * 32 + bx];                // y = bx for whole block
#pragma unroll
        for (int i = 0; i < 2; i++)
#pragma unroll
            for (int r = 0; r < 4; r++) {
                int ml = i * 16 + lg * 4 + r;          // m&31
                float val = accK[i][r] + rw + rel_h[cc * 32 + ml];
                kpos_t[((size_t)(b * 8 + (cc >> 5)) * 1024 + m0 + ml) * 32 + (cc & 31)] = (bf16)val;
            }
    }
    // v: accV[j] row c = c0w+lg*4+r, col m = m0+j*16+lr
#pragma unroll
    for (int j = 0; j < 2; j++) {
        int m = m0 + j * 16 + lr;
#pragma unroll
        for (int r = 0; r < 4; r++) {
            int cc = c0w + lg * 4 + r;
            v_td[((size_t)(b * 8 + (cc >> 5)) * 32 + (cc & 31)) * 1024 + m] = (_Float16)accV[j][r];
        }
    }
#undef LOAD_CHUNK
#undef WRITE_CHUNK
}

// ---------------------------------------------------------------- attention (+q)
// Block = 8 waves x 16 queries = 128 q sharing K/V staged in LDS (512 thr).
// Grid 32x8x4 = 1024 blocks, 33.5KB LDS -> 4 blocks/CU x 8 waves = 32 waves/CU.
// Phase A: fused q = Wq·x (wave-private padded Qs in the staging area).
// K/V staged in 8 chunks of 128 m, double-buffered; T14 split staging.
// K staged at PERMUTED phys rows so per 32-kv block the two QK MFMA outputs
// (s0 over phys[0:16), s1 over phys[16:32)) are already the k=32 fp16 PV
// A-frag: lane (lr,lg) holds P[q=lr][kv=32kb+lg*8+{0..3 | 4..7}]. PV and
// rowsum use mfma_f32_16x16x32_f16 (half the MFMAs, b128 V reads).
__launch_bounds__(512, 8)
__global__ void k_attn(const bf16* __restrict__ xT, const bf16* __restrict__ Wq_bf,
                       const bf16* __restrict__ kpos_t, const _Float16* __restrict__ v_td,
                       float* __restrict__ out) {
    int b = blockIdx.z, h = blockIdx.y;
    int t = threadIdx.x;                               // 0..511
    int w = t >> 6, l = t & 63;                        // 8 waves
    int n0 = blockIdx.x * 128 + w * 16;                // 16 q per wave
    int lr = l & 15, lg = l >> 4;
    const size_t bh = (size_t)(b * 8 + h);
    __shared__ __align__(16) char smem[16384 + 2 * 32 * VSTR * 2];  // 34304 B
    bf16* KsB = (bf16*)smem;                           // 2 bufs x 128x32 (permuted rows)
    _Float16* VsB = (_Float16*)(smem + 16384);         // 2 bufs x 32xVSTR
    const bf16* Kb = kpos_t + bh * 1024 * 32;
    const _Float16* Vb = v_td + bh * 32 * 1024;
    // staging: chunk = 128 m. K: 512 uint4, V: 512 uint4; ONE each per thread.
    uint4 pk_r, pv_r;
#define LOADCH(ch)                                                             \
    {                                                                          \
        pk_r = ((const uint4*)(Kb + (size_t)(ch) * 128 * 32))[t];              \
        pv_r = *(const uint4*)(Vb + (size_t)(t >> 4) * 1024 + (ch) * 128 +     \
                               (t & 15) * 8);                                  \
    }
// K row permutation: within each 32-kv block, kv lands at phys row jl with
// f(jl)=kv: jl = (kv>>3)*4 + (kv&3) + ((kv>>2)&1)*16. Bank-rotate groups by
// permuted row (read side uses koff = ((lr>>1)+lg)&3, invariant mod 4).
#define WRITECH(buf)                                                           \
    {                                                                          \
        int m = t >> 2;                                                        \
        int mb = m & 31;                                                       \
        int jl = ((mb >> 3) << 2) + (mb & 3) + ((mb >> 2) & 1) * 16;           \
        int prow = (m & ~31) + jl;                                             \
        int phys = ((prow >> 1) + (t & 3)) & 3;                                \
        *(uint4*)(&KsB[(buf) * 4096 + prow * 32 + phys * 8]) = pk_r;           \
        *(uint4*)(&VsB[(buf) * (32 * VSTR) + (t >> 4) * VSTR + (t & 15) * 8]) = pv_r; \
    }
    LOADCH(0)                                          // flies under phase A
    // ---- phase A: q[n][d], n in [n0,n0+16), d in [0,32); Qs stride 40
    bf16* Qs = (bf16*)smem + w * 1280;                 // wave-private 16n x 40
    bf16x8 bq0;
    {
        const bf16* Aw = Wq_bf + (size_t)(h * 32 + lr) * 256 + lg * 8;     // rows d
        const bf16* Bx = xT + (size_t)(b * 4096 + n0 + lr) * 256 + lg * 8; // rows n
        f32x4 aq[2] = {};
#pragma unroll
        for (int kk = 0; kk < 8; kk++) {
            bf16x8 a0 = *(const bf16x8*)(Aw + kk * 32);
            bf16x8 a1 = *(const bf16x8*)(Aw + 16 * 256 + kk * 32);
            bf16x8 b0 = *(const bf16x8*)(Bx + kk * 32);
            aq[0] = MFMA16(a0, b0, aq[0], 0, 0, 0);
            aq[1] = MFMA16(a1, b0, aq[1], 0, 0, 0);
        }
        // D[row d = i*16+lg*4+r][col n = lr] -> Qs[n*40 + d], packed b64
#pragma unroll
        for (int i = 0; i < 2; i++) {
            bf16x4 pk;
#pragma unroll
            for (int r = 0; r < 4; r++) pk[r] = (bf16)aq[i][r];
            *(bf16x4*)(Qs + lr * 40 + i * 16 + lg * 4) = pk;
        }
        // same-wave readback (b64 pairs; bank-coprime stride)
        bf16x4 a0 = *(const bf16x4*)(Qs + lr * 40 + lg * 8);
        bf16x4 a1 = *(const bf16x4*)(Qs + lr * 40 + lg * 8 + 4);
#pragma unroll
        for (int e = 0; e < 4; e++) { bq0[e] = a0[e]; bq0[4 + e] = a1[e]; }
    }
    __syncthreads();               // all waves done with Qs before staging clobbers
    WRITECH(0)                     // vmcnt-gated; window = phase A
    LOADCH(1)
    __syncthreads();               // buf0 visible
    f32x4 accO[2] = {};            // [d-tile]: col d = lr, row n = lg*4+r
    f32x4 accS = {};               // row sums (ones-B MFMA): same row layout
    const f16x8 ones8 = {(_Float16)1.f, (_Float16)1.f, (_Float16)1.f, (_Float16)1.f,
                         (_Float16)1.f, (_Float16)1.f, (_Float16)1.f, (_Float16)1.f};
    const f32x4 zs = {-SOFTMAX_SHIFT, -SOFTMAX_SHIFT, -SOFTMAX_SHIFT, -SOFTMAX_SHIFT};
    const int koff = (((lr >> 1) + lg) & 3) * 8;       // read-side swizzle (const/lane)
    for (int ch = 0; ch < 8; ch++) {
        const bf16* Kc = KsB + (ch & 1) * 4096;
        const _Float16* Vc = VsB + (ch & 1) * (32 * VSTR);
        __builtin_amdgcn_s_setprio(1);
#pragma unroll
        for (int kb = 0; kb < 4; kb++) {               // 32-kv block
            // QK over permuted phys rows: s0 -> kv = 32kb+lg*8+r, s1 -> +4+r
            bf16x8 ak0 = *(const bf16x8*)(Kc + (kb * 32 + lr) * 32 + koff);
            bf16x8 ak1 = *(const bf16x8*)(Kc + (kb * 32 + 16 + lr) * 32 + koff);
            f32x4 s0 = MFMA16(ak0, bq0, zs, 0, 0, 0);  // col q=lr
            f32x4 s1 = MFMA16(ak1, bq0, zs, 0, 0, 0);
            // exp2 + RTZ cvt (saturating; s>128 impossible) -> k=32 A-frag
            f16x8 pa;
            {
                fp16x2_raw c01 = __builtin_amdgcn_cvt_pkrtz(
                    __builtin_amdgcn_exp2f(s0[0]), __builtin_amdgcn_exp2f(s0[1]));
                fp16x2_raw c23 = __builtin_amdgcn_cvt_pkrtz(
                    __builtin_amdgcn_exp2f(s0[2]), __builtin_amdgcn_exp2f(s0[3]));
                fp16x2_raw c45 = __builtin_amdgcn_cvt_pkrtz(
                    __builtin_amdgcn_exp2f(s1[0]), __builtin_amdgcn_exp2f(s1[1]));
                fp16x2_raw c67 = __builtin_amdgcn_cvt_pkrtz(
                    __builtin_amdgcn_exp2f(s1[2]), __builtin_amdgcn_exp2f(s1[3]));
                pa[0] = c01[0]; pa[1] = c01[1]; pa[2] = c23[0]; pa[3] = c23[1];
                pa[4] = c45[0]; pa[5] = c45[1]; pa[6] = c67[0]; pa[7] = c67[1];
            }
            // V as B-operand (k=32): B row = d, k = kv = 32kb+lg*8+e, b128
            f16x8 v0 = *(const f16x8*)(Vc + lr * VSTR + kb * 32 + lg * 8);
            f16x8 v1 = *(const f16x8*)(Vc + (16 + lr) * VSTR + kb * 32 + lg * 8);
            accO[0] = MFMA16H32(pa, v0, accO[0], 0, 0, 0);
            accO[1] = MFMA16H32(pa, v1, accO[1], 0, 0, 0);
            accS    = MFMA16H32(pa, ones8, accS, 0, 0, 0);
        }
        __builtin_amdgcn_s_setprio(0);
        if (ch < 7) {
            WRITECH((ch + 1) & 1)                      // vmcnt-gated, sunk after compute
            if (ch < 6) LOADCH(ch + 2)                 // in flight across next barrier
            __syncthreads();
        }
    }
#undef LOADCH
#undef WRITECH
    // accS[r] = rowsum(n = lg*4+r), duplicated across cols — no shuffles needed
    float inv[4];
#pragma unroll
    for (int r = 0; r < 4; r++) inv[r] = 1.0f / accS[r];
#pragma unroll
    for (int dt = 0; dt < 2; dt++) {
        int c = h * 32 + dt * 16 + lr;                 // accO col = d = lr
        float* op = out + (size_t)(b * 256 + c) * 4096 + n0 + lg * 4;
        f32x4 o;
#pragma unroll
        for (int r = 0; r < 4; r++) o[r] = accO[dt][r] * inv[r];
        *(f32x4*)op = o;
    }
}

// ---------------------------------------------------------------- launcher
extern "C" void kernel_launch(void* const* d_in, const int* in_sizes, int n_in,
                              void* d_out, int out_size, void* d_ws, size_t ws_size,
                              hipStream_t stream) {
    const float* x    = (const float*)d_in[0];
    const float* Wq   = (const float*)d_in[1];
    const float* Wk   = (const float*)d_in[2];
    const float* Wv   = (const float*)d_in[3];
    const float* relh = (const float*)d_in[4];
    const float* relw = (const float*)d_in[5];
    float* out = (float*)d_out;
    char* ws = (char*)d_ws;

    bf16*      xT     = (bf16*)(ws);                                  // 8 MiB
    bf16*      kposT  = (bf16*)(ws + (8u << 20));                     // 2 MiB
    _Float16*  v_td   = (_Float16*)(ws + (10u << 20));                // 2 MiB
    bf16*      Wq_bf  = (bf16*)(ws + (12u << 20));                    // 128 KiB
    bf16*      Wkv_bf = (bf16*)(ws + (12u << 20) + (256u << 10));     // 1 MiB

    k_prep_w <<<192,            256, 0, stream>>>(Wq, Wk, Wv, Wq_bf, Wkv_bf);
    k_xT     <<<dim3(64, 4, 4), 256, 0, stream>>>(x, xT);
    k_gemm_kv<<<dim3(32, 4, 4), 256, 0, stream>>>(xT, Wkv_bf, relh, relw, kposT, v_td);
    k_attn   <<<dim3(32, 8, 4), 512, 0, stream>>>(xT, Wq_bf, kposT, v_td, out);
}

// Round 7
// 145.270 us; speedup vs baseline: 1.2763x; 1.2763x over previous
//
#include <hip/hip_runtime.h>
#include <math.h>

// MHSA_27582279975470 — bf16/fp16 MFMA pipeline for MI355X (gfx950)
// B=4, C=256, NH=8, HD=32, H=W=64 -> Nq=4096, SR=2 -> Mkv=1024
//
// R18 = R17 resubmitted (R17's bench failed on container acquisition, not
// the kernel). Fix for R16's regression (44.5 -> 85us): misaligned
// ds_read_b128. R16 widened V reads to f16x8 (16B) but kept VSTR=140: byte
// addr lr*280 is 8 mod 16 for odd lr -> misaligned b128 slow path
// (invisible to the bank-conflict counter; both pipes did identical
// absolute work in 2x the time = pure wait-stall on the V datapath).
// VSTR=136: lr*272 = 0 mod 16 (aligned), dword stride 68 = 4 mod 32 ->
// b128 reads/writes hit the uniform 4-touches/bank floor. (R14's
// 136-problem was b64-specific.) Everything else identical to R16: k=32
// fp16 PV MFMAs (12/chunk vs 24), K staged at permuted phys rows so QK
// outputs are already the k=32 A-frag, b128 V reads, T14 split staging,
// one barrier per chunk. k_prep_w / k_xT / k_gemm_kv byte-identical.

typedef __bf16 bf16;
typedef __attribute__((ext_vector_type(4))) __bf16 bf16x4;
typedef __attribute__((ext_vector_type(8))) __bf16 bf16x8;
typedef __attribute__((ext_vector_type(4))) float f32x4;
typedef __attribute__((ext_vector_type(2))) __fp16 fp16x2_raw;   // cvt_pkrtz ret type
typedef __attribute__((ext_vector_type(4))) _Float16 f16x4;
typedef __attribute__((ext_vector_type(8))) _Float16 f16x8;

#define MFMA16 __builtin_amdgcn_mfma_f32_16x16x32_bf16      // D[row=A-row][col=B-row]
#define MFMA16H32 __builtin_amdgcn_mfma_f32_16x16x32_f16    // k=32, fp16 in (gfx950)

#define QSCALE 0.25503486f   // (1/sqrt(32)) * log2(e)
#define SOFTMAX_SHIFT 10.0f  // constant exp2-domain shift (softmax-invariant)
#define VSTR 136             // Vs row stride in f16: 272B rows -> b128-aligned,
                             // dword stride 68 (4 mod 32) -> floor-uniform banks

// ---------------------------------------------------------------- prep weights
__global__ void k_prep_w(const float* __restrict__ Wq, const float* __restrict__ Wk,
                         const float* __restrict__ Wv,
                         bf16* __restrict__ Wq_bf, bf16* __restrict__ Wkv_bf) {
    int tid = blockIdx.x * 256 + threadIdx.x;          // 0..49151
    if (tid < 32768) {
        // Wkv: thread handles (c, i4): 4 rows i, all 4 taps
        int c = tid >> 6, i4 = (tid & 63) * 4;         // c: 0..511 (k then v)
        const float* Wsrc = (c < 256) ? Wk : Wv;
        int cs = c & 255;
        f32x4 r[4];
#pragma unroll
        for (int j = 0; j < 4; j++)
            r[j] = ((const f32x4*)Wsrc)[cs * 256 + i4 + j];   // W[cs][i4+j][0..3]
#pragma unroll
        for (int tap = 0; tap < 4; tap++) {            // K-order: tap*256 + i
            bf16x4 o;
#pragma unroll
            for (int j = 0; j < 4; j++) o[j] = (bf16)r[j][tap];
            *(bf16x4*)(Wkv_bf + c * 1024 + tap * 256 + i4) = o;
        }
    } else {
        int q = tid - 32768;                           // 0..16383
        f32x4 q4 = ((const f32x4*)Wq)[q];
        bf16x4 o;
#pragma unroll
        for (int e = 0; e < 4; e++) o[e] = (bf16)(q4[e] * QSCALE);
        *(bf16x4*)(Wq_bf + q * 4) = o;                 // fold scale*log2e into q
    }
}

// ---------------------------------------------------------------- x transpose
__global__ void k_xT(const float* __restrict__ x, bf16* __restrict__ xT) {
    // grid (64 n-tiles, 4 c-tiles, 4 b), 256 thr, 64x64 tile
    int b = blockIdx.z, c0 = blockIdx.y * 64, n0 = blockIdx.x * 64;
    __shared__ float tile[64][65];                     // stride 65: bank-rotating
    int t = threadIdx.x;
    const float* xp = x + (size_t)(b * 256 + c0) * 4096 + n0;
    // load: 64 c-rows x 16 float4; 4 units/thread
#pragma unroll
    for (int it = 0; it < 4; it++) {
        int u = it * 256 + t;
        int row = u >> 4, colq = u & 15;               // row = c-local
        f32x4 v = *(const f32x4*)(xp + (size_t)row * 4096 + colq * 4);
#pragma unroll
        for (int e = 0; e < 4; e++) tile[row][colq * 4 + e] = v[e];
    }
    __syncthreads();
    bf16* op = xT + (size_t)(b * 4096 + n0) * 256 + c0;
    // store: 64 n-rows x 8 groups of 8 c; 2 units/thread, 16B stores
#pragma unroll
    for (int it = 0; it < 2; it++) {
        int u = it * 256 + t;
        int orow = u >> 3, oc8 = (u & 7) * 8;          // orow = n-local
        bf16x8 o;
#pragma unroll
        for (int e = 0; e < 8; e++) o[e] = (bf16)tile[oc8 + e][orow];
        *(bf16x8*)(op + (size_t)orow * 256 + oc8) = o;
    }
}

// ---------------------------------------------------------------- kv conv GEMM
// Block = 32 m x 64 c, computes BOTH kpos and v (P-frags shared between the
// two GEMMs). P rows staged in LDS (dbuf 2x16.5KB, reg-prefetch); each chunk
// = one tap (256 k). Weights read from global (1MB, L2-resident).
__launch_bounds__(256)
__global__ void k_gemm_kv(const bf16* __restrict__ xT, const bf16* __restrict__ Wkv_bf,
                          const float* __restrict__ rel_h, const float* __restrict__ rel_w,
                          bf16* __restrict__ kpos_t, _Float16* __restrict__ v_td) {
    int b = blockIdx.z;
    int bx = blockIdx.x;                               // m-tile: m0 = bx*32, y = bx
    int m0 = bx * 32;
    int c0w = blockIdx.y * 64 + (threadIdx.x >> 6) * 16;
    int t = threadIdx.x, l = t & 63;
    int lr = l & 15, lg = l >> 4;
    __shared__ __align__(16) bf16 Ps[2][32 * 264];     // row stride 264 (+8 pad)
    const bf16* xb = xT + (size_t)b * 4096 * 256;
    int srow = t >> 3;                                 // 4 units/thread: rows t>>3
    int scu0 = (t & 7) * 4;                            // cols (t&7)*4 .. +3
    uint4 pre[4];
#define LOAD_CHUNK(tap)                                                        \
    {                                                                          \
        int dy = (tap) >> 1, dx = (tap) & 1;                                   \
        const bf16* src = xb + (size_t)((2 * bx + dy) * 64 + 2 * srow + dx) * 256; \
        _Pragma("unroll")                                                      \
        for (int j = 0; j < 4; j++)                                            \
            pre[j] = *(const uint4*)(src + (scu0 + j) * 8);                    \
    }
#define WRITE_CHUNK(buf)                                                       \
    {                                                                          \
        bf16* dst = Ps[buf] + srow * 264 + scu0 * 8;                           \
        _Pragma("unroll")                                                      \
        for (int j = 0; j < 4; j++) *(uint4*)(dst + j * 8) = pre[j];           \
    }
    LOAD_CHUNK(0)
    WRITE_CHUNK(0)
    const bf16* Gkb = Wkv_bf + (size_t)(c0w + lr) * 1024 + lg * 8;
    const bf16* Gvb = Gkb + 256 * 1024;
    f32x4 accK[2] = {}, accV[2] = {};
    for (int ch = 0; ch < 4; ch++) {
        if (ch < 3) LOAD_CHUNK(ch + 1)
        __syncthreads();
        const bf16* P = Ps[ch & 1];
#pragma unroll
        for (int kk = 0; kk < 8; kk++) {
            bf16x8 pa0 = *(const bf16x8*)(P + lr * 264 + kk * 32 + lg * 8);
            bf16x8 pa1 = *(const bf16x8*)(P + (16 + lr) * 264 + kk * 32 + lg * 8);
            bf16x8 gk = *(const bf16x8*)(Gkb + ch * 256 + kk * 32);
            bf16x8 gv = *(const bf16x8*)(Gvb + ch * 256 + kk * 32);
            accK[0] = MFMA16(pa0, gk, accK[0], 0, 0, 0);
            accK[1] = MFMA16(pa1, gk, accK[1], 0, 0, 0);
            accV[0] = MFMA16(gv, pa0, accV[0], 0, 0, 0);
            accV[1] = MFMA16(gv, pa1, accV[1], 0, 0, 0);
        }
        if (ch < 3) {
            __syncthreads();
            WRITE_CHUNK((ch + 1) & 1)
        }
    }
    // kpos: accK[i] row m = m0+i*16+lg*4+r, col c = c0w+lr
    {
        int cc = c0w + lr;
        float rw = rel_w[cc * 32 + bx];                // y = bx for whole block
#pragma unroll
        for (int i = 0; i < 2; i++)
#pragma unroll
            for (int r = 0; r < 4; r++) {
                int ml = i * 16 + lg * 4 + r;          // m&31
                float val = accK[i][r] + rw + rel_h[cc * 32 + ml];
                kpos_t[((size_t)(b * 8 + (cc >> 5)) * 1024 + m0 + ml) * 32 + (cc & 31)] = (bf16)val;
            }
    }
    // v: accV[j] row c = c0w+lg*4+r, col m = m0+j*16+lr
#pragma unroll
    for (int j = 0; j < 2; j++) {
        int m = m0 + j * 16 + lr;
#pragma unroll
        for (int r = 0; r < 4; r++) {
            int cc = c0w + lg * 4 + r;
            v_td[((size_t)(b * 8 + (cc >> 5)) * 32 + (cc & 31)) * 1024 + m] = (_Float16)accV[j][r];
        }
    }
#undef LOAD_CHUNK
#undef WRITE_CHUNK
}

// ---------------------------------------------------------------- attention (+q)
// Block = 8 waves x 16 queries = 128 q sharing K/V staged in LDS (512 thr).
// Grid 32x8x4 = 1024 blocks, 33KB LDS -> 4 blocks/CU x 8 waves = 32 waves/CU.
// Phase A: fused q = Wq·x (wave-private padded Qs in the staging area).
// K/V staged in 8 chunks of 128 m, double-buffered; T14 split staging.
// K staged at PERMUTED phys rows so per 32-kv block the two QK MFMA outputs
// (s0 over phys[0:16), s1 over phys[16:32)) are already the k=32 fp16 PV
// A-frag: lane (lr,lg) holds P[q=lr][kv=32kb+lg*8+{0..3 | 4..7}]. PV and
// rowsum use mfma_f32_16x16x32_f16 (half the MFMAs, ALIGNED b128 V reads).
__launch_bounds__(512, 8)
__global__ void k_attn(const bf16* __restrict__ xT, const bf16* __restrict__ Wq_bf,
                       const bf16* __restrict__ kpos_t, const _Float16* __restrict__ v_td,
                       float* __restrict__ out) {
    int b = blockIdx.z, h = blockIdx.y;
    int t = threadIdx.x;                               // 0..511
    int w = t >> 6, l = t & 63;                        // 8 waves
    int n0 = blockIdx.x * 128 + w * 16;                // 16 q per wave
    int lr = l & 15, lg = l >> 4;
    const size_t bh = (size_t)(b * 8 + h);
    __shared__ __align__(16) char smem[16384 + 2 * 32 * VSTR * 2];  // 33792 B
    bf16* KsB = (bf16*)smem;                           // 2 bufs x 128x32 (permuted rows)
    _Float16* VsB = (_Float16*)(smem + 16384);         // 2 bufs x 32xVSTR
    const bf16* Kb = kpos_t + bh * 1024 * 32;
    const _Float16* Vb = v_td + bh * 32 * 1024;
    // staging: chunk = 128 m. K: 512 uint4, V: 512 uint4; ONE each per thread.
    uint4 pk_r, pv_r;
#define LOADCH(ch)                                                             \
    {                                                                          \
        pk_r = ((const uint4*)(Kb + (size_t)(ch) * 128 * 32))[t];              \
        pv_r = *(const uint4*)(Vb + (size_t)(t >> 4) * 1024 + (ch) * 128 +     \
                               (t & 15) * 8);                                  \
    }
// K row permutation: within each 32-kv block, kv lands at phys row jl with
// f(jl)=kv: jl = (kv>>3)*4 + (kv&3) + ((kv>>2)&1)*16. Bank-rotate groups by
// permuted row (read side uses koff = ((lr>>1)+lg)&3, invariant mod 4).
#define WRITECH(buf)                                                           \
    {                                                                          \
        int m = t >> 2;                                                        \
        int mb = m & 31;                                                       \
        int jl = ((mb >> 3) << 2) + (mb & 3) + ((mb >> 2) & 1) * 16;           \
        int prow = (m & ~31) + jl;                                             \
        int phys = ((prow >> 1) + (t & 3)) & 3;                                \
        *(uint4*)(&KsB[(buf) * 4096 + prow * 32 + phys * 8]) = pk_r;           \
        *(uint4*)(&VsB[(buf) * (32 * VSTR) + (t >> 4) * VSTR + (t & 15) * 8]) = pv_r; \
    }
    LOADCH(0)                                          // flies under phase A
    // ---- phase A: q[n][d], n in [n0,n0+16), d in [0,32); Qs stride 40
    bf16* Qs = (bf16*)smem + w * 1280;                 // wave-private 16n x 40
    bf16x8 bq0;
    {
        const bf16* Aw = Wq_bf + (size_t)(h * 32 + lr) * 256 + lg * 8;     // rows d
        const bf16* Bx = xT + (size_t)(b * 4096 + n0 + lr) * 256 + lg * 8; // rows n
        f32x4 aq[2] = {};
#pragma unroll
        for (int kk = 0; kk < 8; kk++) {
            bf16x8 a0 = *(const bf16x8*)(Aw + kk * 32);
            bf16x8 a1 = *(const bf16x8*)(Aw + 16 * 256 + kk * 32);
            bf16x8 b0 = *(const bf16x8*)(Bx + kk * 32);
            aq[0] = MFMA16(a0, b0, aq[0], 0, 0, 0);
            aq[1] = MFMA16(a1, b0, aq[1], 0, 0, 0);
        }
        // D[row d = i*16+lg*4+r][col n = lr] -> Qs[n*40 + d], packed b64
#pragma unroll
        for (int i = 0; i < 2; i++) {
            bf16x4 pk;
#pragma unroll
            for (int r = 0; r < 4; r++) pk[r] = (bf16)aq[i][r];
            *(bf16x4*)(Qs + lr * 40 + i * 16 + lg * 4) = pk;
        }
        // same-wave readback (b64 pairs; bank-coprime stride)
        bf16x4 a0 = *(const bf16x4*)(Qs + lr * 40 + lg * 8);
        bf16x4 a1 = *(const bf16x4*)(Qs + lr * 40 + lg * 8 + 4);
#pragma unroll
        for (int e = 0; e < 4; e++) { bq0[e] = a0[e]; bq0[4 + e] = a1[e]; }
    }
    __syncthreads();               // all waves done with Qs before staging clobbers
    WRITECH(0)                     // vmcnt-gated; window = phase A
    LOADCH(1)
    __syncthreads();               // buf0 visible
    f32x4 accO[2] = {};            // [d-tile]: col d = lr, row n = lg*4+r
    f32x4 accS = {};               // row sums (ones-B MFMA): same row layout
    const f16x8 ones8 = {(_Float16)1.f, (_Float16)1.f, (_Float16)1.f, (_Float16)1.f,
                         (_Float16)1.f, (_Float16)1.f, (_Float16)1.f, (_Float16)1.f};
    const f32x4 zs = {-SOFTMAX_SHIFT, -SOFTMAX_SHIFT, -SOFTMAX_SHIFT, -SOFTMAX_SHIFT};
    const int koff = (((lr >> 1) + lg) & 3) * 8;       // read-side swizzle (const/lane)
    for (int ch = 0; ch < 8; ch++) {
        const bf16* Kc = KsB + (ch & 1) * 4096;
        const _Float16* Vc = VsB + (ch & 1) * (32 * VSTR);
        __builtin_amdgcn_s_setprio(1);
#pragma unroll
        for (int kb = 0; kb < 4; kb++) {               // 32-kv block
            // QK over permuted phys rows: s0 -> kv = 32kb+lg*8+r, s1 -> +4+r
            bf16x8 ak0 = *(const bf16x8*)(Kc + (kb * 32 + lr) * 32 + koff);
            bf16x8 ak1 = *(const bf16x8*)(Kc + (kb * 32 + 16 + lr) * 32 + koff);
            f32x4 s0 = MFMA16(ak0, bq0, zs, 0, 0, 0);  // col q=lr
            f32x4 s1 = MFMA16(ak1, bq0, zs, 0, 0, 0);
            // exp2 + RTZ cvt (saturating; s>128 impossible) -> k=32 A-frag
            f16x8 pa;
            {
                fp16x2_raw c01 = __builtin_amdgcn_cvt_pkrtz(
                    __builtin_amdgcn_exp2f(s0[0]), __builtin_amdgcn_exp2f(s0[1]));
                fp16x2_raw c23 = __builtin_amdgcn_cvt_pkrtz(
                    __builtin_amdgcn_exp2f(s0[2]), __builtin_amdgcn_exp2f(s0[3]));
                fp16x2_raw c45 = __builtin_amdgcn_cvt_pkrtz(
                    __builtin_amdgcn_exp2f(s1[0]), __builtin_amdgcn_exp2f(s1[1]));
                fp16x2_raw c67 = __builtin_amdgcn_cvt_pkrtz(
                    __builtin_amdgcn_exp2f(s1[2]), __builtin_amdgcn_exp2f(s1[3]));
                pa[0] = c01[0]; pa[1] = c01[1]; pa[2] = c23[0]; pa[3] = c23[1];
                pa[4] = c45[0]; pa[5] = c45[1]; pa[6] = c67[0]; pa[7] = c67[1];
            }
            // V as B-operand (k=32): B row = d, k = kv = 32kb+lg*8+e, b128
            f16x8 v0 = *(const f16x8*)(Vc + lr * VSTR + kb * 32 + lg * 8);
            f16x8 v1 = *(const f16x8*)(Vc + (16 + lr) * VSTR + kb * 32 + lg * 8);
            accO[0] = MFMA16H32(pa, v0, accO[0], 0, 0, 0);
            accO[1] = MFMA16H32(pa, v1, accO[1], 0, 0, 0);
            accS    = MFMA16H32(pa, ones8, accS, 0, 0, 0);
        }
        __builtin_amdgcn_s_setprio(0);
        if (ch < 7) {
            WRITECH((ch + 1) & 1)                      // vmcnt-gated, sunk after compute
            if (ch < 6) LOADCH(ch + 2)                 // in flight across next barrier
            __syncthreads();
        }
    }
#undef LOADCH
#undef WRITECH
    // accS[r] = rowsum(n = lg*4+r), duplicated across cols — no shuffles needed
    float inv[4];
#pragma unroll
    for (int r = 0; r < 4; r++) inv[r] = 1.0f / accS[r];
#pragma unroll
    for (int dt = 0; dt < 2; dt++) {
        int c = h * 32 + dt * 16 + lr;                 // accO col = d = lr
        float* op = out + (size_t)(b * 256 + c) * 4096 + n0 + lg * 4;
        f32x4 o;
#pragma unroll
        for (int r = 0; r < 4; r++) o[r] = accO[dt][r] * inv[r];
        *(f32x4*)op = o;
    }
}

// ---------------------------------------------------------------- launcher
extern "C" void kernel_launch(void* const* d_in, const int* in_sizes, int n_in,
                              void* d_out, int out_size, void* d_ws, size_t ws_size,
                              hipStream_t stream) {
    const float* x    = (const float*)d_in[0];
    const float* Wq   = (const float*)d_in[1];
    const float* Wk   = (const float*)d_in[2];
    const float* Wv   = (const float*)d_in[3];
    const float* relh = (const float*)d_in[4];
    const float* relw = (const float*)d_in[5];
    float* out = (float*)d_out;
    char* ws = (char*)d_ws;

    bf16*      xT     = (bf16*)(ws);                                  // 8 MiB
    bf16*      kposT  = (bf16*)(ws + (8u << 20));                     // 2 MiB
    _Float16*  v_td   = (_Float16*)(ws + (10u << 20));                // 2 MiB
    bf16*      Wq_bf  = (bf16*)(ws + (12u << 20));                    // 128 KiB
    bf16*      Wkv_bf = (bf16*)(ws + (12u << 20) + (256u << 10));     // 1 MiB

    k_prep_w <<<192,            256, 0, stream>>>(Wq, Wk, Wv, Wq_bf, Wkv_bf);
    k_xT     <<<dim3(64, 4, 4), 256, 0, stream>>>(x, xT);
    k_gemm_kv<<<dim3(32, 4, 4), 256, 0, stream>>>(xT, Wkv_bf, relh, relw, kposT, v_td);
    k_attn   <<<dim3(32, 8, 4), 512, 0, stream>>>(xT, Wq_bf, kposT, v_td, out);
}

// Round 8
// 140.989 us; speedup vs baseline: 1.3151x; 1.0304x over previous
//
#include <hip/hip_runtime.h>
#include <math.h>

// MHSA_27582279975470 — bf16/fp16 MFMA pipeline for MI355X (gfx950)
// B=4, C=256, NH=8, HD=32, H=W=64 -> Nq=4096, SR=2 -> Mkv=1024
//
// R19: k_attn 8x16q -> 4x32q (256 thr). Per-wave LDS read volume is fixed
// (full K/V sweep = 128KB/wave), so halving wave count halves total LDS
// read traffic (~17us -> ~8.5us at the 69TB/s ceiling) — the largest
// identified component of attn's 42us. K/V ds_reads + staging shared by
// both q-halves. VGPR cap doubles to 128 (__launch_bounds__(256,4), 4
// blocks/CU x 4 waves = 16 waves/CU) — no spill risk at ~90 live VGPR.
// Carried over: VSTR=136 (b128-aligned, bank-floor; proven R18), K phys-row
// permute -> k=32 fp16 PV MFMAs, T14 split staging, 1 barrier/chunk,
// setprio around compute. Phase A = proven R0 2x2 form.
// k_prep_w / k_xT / k_gemm_kv byte-identical.

typedef __bf16 bf16;
typedef __attribute__((ext_vector_type(4))) __bf16 bf16x4;
typedef __attribute__((ext_vector_type(8))) __bf16 bf16x8;
typedef __attribute__((ext_vector_type(4))) float f32x4;
typedef __attribute__((ext_vector_type(2))) __fp16 fp16x2_raw;   // cvt_pkrtz ret type
typedef __attribute__((ext_vector_type(4))) _Float16 f16x4;
typedef __attribute__((ext_vector_type(8))) _Float16 f16x8;

#define MFMA16 __builtin_amdgcn_mfma_f32_16x16x32_bf16      // D[row=A-row][col=B-row]
#define MFMA16H32 __builtin_amdgcn_mfma_f32_16x16x32_f16    // k=32, fp16 in (gfx950)

#define QSCALE 0.25503486f   // (1/sqrt(32)) * log2(e)
#define SOFTMAX_SHIFT 10.0f  // constant exp2-domain shift (softmax-invariant)
#define VSTR 136             // Vs row stride in f16: 272B rows -> b128-aligned,
                             // dword stride 68 (4 mod 32) -> floor-uniform banks

// ---------------------------------------------------------------- prep weights
__global__ void k_prep_w(const float* __restrict__ Wq, const float* __restrict__ Wk,
                         const float* __restrict__ Wv,
                         bf16* __restrict__ Wq_bf, bf16* __restrict__ Wkv_bf) {
    int tid = blockIdx.x * 256 + threadIdx.x;          // 0..49151
    if (tid < 32768) {
        // Wkv: thread handles (c, i4): 4 rows i, all 4 taps
        int c = tid >> 6, i4 = (tid & 63) * 4;         // c: 0..511 (k then v)
        const float* Wsrc = (c < 256) ? Wk : Wv;
        int cs = c & 255;
        f32x4 r[4];
#pragma unroll
        for (int j = 0; j < 4; j++)
            r[j] = ((const f32x4*)Wsrc)[cs * 256 + i4 + j];   // W[cs][i4+j][0..3]
#pragma unroll
        for (int tap = 0; tap < 4; tap++) {            // K-order: tap*256 + i
            bf16x4 o;
#pragma unroll
            for (int j = 0; j < 4; j++) o[j] = (bf16)r[j][tap];
            *(bf16x4*)(Wkv_bf + c * 1024 + tap * 256 + i4) = o;
        }
    } else {
        int q = tid - 32768;                           // 0..16383
        f32x4 q4 = ((const f32x4*)Wq)[q];
        bf16x4 o;
#pragma unroll
        for (int e = 0; e < 4; e++) o[e] = (bf16)(q4[e] * QSCALE);
        *(bf16x4*)(Wq_bf + q * 4) = o;                 // fold scale*log2e into q
    }
}

// ---------------------------------------------------------------- x transpose
__global__ void k_xT(const float* __restrict__ x, bf16* __restrict__ xT) {
    // grid (64 n-tiles, 4 c-tiles, 4 b), 256 thr, 64x64 tile
    int b = blockIdx.z, c0 = blockIdx.y * 64, n0 = blockIdx.x * 64;
    __shared__ float tile[64][65];                     // stride 65: bank-rotating
    int t = threadIdx.x;
    const float* xp = x + (size_t)(b * 256 + c0) * 4096 + n0;
    // load: 64 c-rows x 16 float4; 4 units/thread
#pragma unroll
    for (int it = 0; it < 4; it++) {
        int u = it * 256 + t;
        int row = u >> 4, colq = u & 15;               // row = c-local
        f32x4 v = *(const f32x4*)(xp + (size_t)row * 4096 + colq * 4);
#pragma unroll
        for (int e = 0; e < 4; e++) tile[row][colq * 4 + e] = v[e];
    }
    __syncthreads();
    bf16* op = xT + (size_t)(b * 4096 + n0) * 256 + c0;
    // store: 64 n-rows x 8 groups of 8 c; 2 units/thread, 16B stores
#pragma unroll
    for (int it = 0; it < 2; it++) {
        int u = it * 256 + t;
        int orow = u >> 3, oc8 = (u & 7) * 8;          // orow = n-local
        bf16x8 o;
#pragma unroll
        for (int e = 0; e < 8; e++) o[e] = (bf16)tile[oc8 + e][orow];
        *(bf16x8*)(op + (size_t)orow * 256 + oc8) = o;
    }
}

// ---------------------------------------------------------------- kv conv GEMM
// Block = 32 m x 64 c, computes BOTH kpos and v (P-frags shared between the
// two GEMMs). P rows staged in LDS (dbuf 2x16.5KB, reg-prefetch); each chunk
// = one tap (256 k). Weights read from global (1MB, L2-resident).
__launch_bounds__(256)
__global__ void k_gemm_kv(const bf16* __restrict__ xT, const bf16* __restrict__ Wkv_bf,
                          const float* __restrict__ rel_h, const float* __restrict__ rel_w,
                          bf16* __restrict__ kpos_t, _Float16* __restrict__ v_td) {
    int b = blockIdx.z;
    int bx = blockIdx.x;                               // m-tile: m0 = bx*32, y = bx
    int m0 = bx * 32;
    int c0w = blockIdx.y * 64 + (threadIdx.x >> 6) * 16;
    int t = threadIdx.x, l = t & 63;
    int lr = l & 15, lg = l >> 4;
    __shared__ __align__(16) bf16 Ps[2][32 * 264];     // row stride 264 (+8 pad)
    const bf16* xb = xT + (size_t)b * 4096 * 256;
    int srow = t >> 3;                                 // 4 units/thread: rows t>>3
    int scu0 = (t & 7) * 4;                            // cols (t&7)*4 .. +3
    uint4 pre[4];
#define LOAD_CHUNK(tap)                                                        \
    {                                                                          \
        int dy = (tap) >> 1, dx = (tap) & 1;                                   \
        const bf16* src = xb + (size_t)((2 * bx + dy) * 64 + 2 * srow + dx) * 256; \
        _Pragma("unroll")                                                      \
        for (int j = 0; j < 4; j++)                                            \
            pre[j] = *(const uint4*)(src + (scu0 + j) * 8);                    \
    }
#define WRITE_CHUNK(buf)                                                       \
    {                                                                          \
        bf16* dst = Ps[buf] + srow * 264 + scu0 * 8;                           \
        _Pragma("unroll")                                                      \
        for (int j = 0; j < 4; j++) *(uint4*)(dst + j * 8) = pre[j];           \
    }
    LOAD_CHUNK(0)
    WRITE_CHUNK(0)
    const bf16* Gkb = Wkv_bf + (size_t)(c0w + lr) * 1024 + lg * 8;
    const bf16* Gvb = Gkb + 256 * 1024;
    f32x4 accK[2] = {}, accV[2] = {};
    for (int ch = 0; ch < 4; ch++) {
        if (ch < 3) LOAD_CHUNK(ch + 1)
        __syncthreads();
        const bf16* P = Ps[ch & 1];
#pragma unroll
        for (int kk = 0; kk < 8; kk++) {
            bf16x8 pa0 = *(const bf16x8*)(P + lr * 264 + kk * 32 + lg * 8);
            bf16x8 pa1 = *(const bf16x8*)(P + (16 + lr) * 264 + kk * 32 + lg * 8);
            bf16x8 gk = *(const bf16x8*)(Gkb + ch * 256 + kk * 32);
            bf16x8 gv = *(const bf16x8*)(Gvb + ch * 256 + kk * 32);
            accK[0] = MFMA16(pa0, gk, accK[0], 0, 0, 0);
            accK[1] = MFMA16(pa1, gk, accK[1], 0, 0, 0);
            accV[0] = MFMA16(gv, pa0, accV[0], 0, 0, 0);
            accV[1] = MFMA16(gv, pa1, accV[1], 0, 0, 0);
        }
        if (ch < 3) {
            __syncthreads();
            WRITE_CHUNK((ch + 1) & 1)
        }
    }
    // kpos: accK[i] row m = m0+i*16+lg*4+r, col c = c0w+lr
    {
        int cc = c0w + lr;
        float rw = rel_w[cc * 32 + bx];                // y = bx for whole block
#pragma unroll
        for (int i = 0; i < 2; i++)
#pragma unroll
            for (int r = 0; r < 4; r++) {
                int ml = i * 16 + lg * 4 + r;          // m&31
                float val = accK[i][r] + rw + rel_h[cc * 32 + ml];
                kpos_t[((size_t)(b * 8 + (cc >> 5)) * 1024 + m0 + ml) * 32 + (cc & 31)] = (bf16)val;
            }
    }
    // v: accV[j] row c = c0w+lg*4+r, col m = m0+j*16+lr
#pragma unroll
    for (int j = 0; j < 2; j++) {
        int m = m0 + j * 16 + lr;
#pragma unroll
        for (int r = 0; r < 4; r++) {
            int cc = c0w + lg * 4 + r;
            v_td[((size_t)(b * 8 + (cc >> 5)) * 32 + (cc & 31)) * 1024 + m] = (_Float16)accV[j][r];
        }
    }
#undef LOAD_CHUNK
#undef WRITE_CHUNK
}

// ---------------------------------------------------------------- attention (+q)
// Block = 4 waves x 32 queries = 128 q sharing K/V staged in LDS (256 thr).
// Grid 32x8x4 = 1024 blocks, 33KB LDS -> 4 blocks/CU x 4 waves = 16 waves/CU
// (halved vs R18 — but total LDS read traffic also halves: per-wave K/V
// sweep is fixed at 128KB, so traffic = waves x 128KB). VGPR cap 128.
// Phase A: fused q = Wq·x (2x2 MFMA, wave-private Qs). K/V staged in 8
// chunks of 128 m, double-buffered, T14 split, one barrier per chunk.
// K staged at PERMUTED phys rows -> QK outputs land in the k=32 fp16 PV
// A-frag layout. ds_reads (ak0/ak1, v0/v1) shared across both q-halves.
__launch_bounds__(256, 4)
__global__ void k_attn(const bf16* __restrict__ xT, const bf16* __restrict__ Wq_bf,
                       const bf16* __restrict__ kpos_t, const _Float16* __restrict__ v_td,
                       float* __restrict__ out) {
    int b = blockIdx.z, h = blockIdx.y;
    int t = threadIdx.x;                               // 0..255
    int w = t >> 6, l = t & 63;                        // 4 waves
    int n0 = blockIdx.x * 128 + w * 32;                // 32 q per wave
    int lr = l & 15, lg = l >> 4;
    const size_t bh = (size_t)(b * 8 + h);
    __shared__ __align__(16) char smem[16384 + 2 * 32 * VSTR * 2];  // 33792 B
    bf16* KsB = (bf16*)smem;                           // 2 bufs x 128x32 (permuted rows)
    _Float16* VsB = (_Float16*)(smem + 16384);         // 2 bufs x 32xVSTR
    const bf16* Kb = kpos_t + bh * 1024 * 32;
    const _Float16* Vb = v_td + bh * 32 * 1024;
    // staging: chunk = 128 m. K: 512 uint4, V: 512 uint4; TWO each per thread.
    uint4 pk_r0, pk_r1, pv_r0, pv_r1;
#define LOADCH(ch)                                                             \
    {                                                                          \
        const uint4* ksrc = (const uint4*)(Kb + (size_t)(ch) * 128 * 32);      \
        pk_r0 = ksrc[t];                                                       \
        pk_r1 = ksrc[t + 256];                                                 \
        pv_r0 = *(const uint4*)(Vb + (size_t)(t >> 4) * 1024 + (ch) * 128 +    \
                                (t & 15) * 8);                                 \
        pv_r1 = *(const uint4*)(Vb + (size_t)((t + 256) >> 4) * 1024 +         \
                                (ch) * 128 + (t & 15) * 8);                    \
    }
// K row permutation: within each 32-kv block, kv lands at phys row jl with
// f(jl)=kv: jl = (kv>>3)*4 + (kv&3) + ((kv>>2)&1)*16. Bank-rotate groups by
// permuted row (read side uses koff = ((lr>>1)+lg)&3, invariant mod 4).
#define KWR(uu, reg)                                                           \
    {                                                                          \
        int m = (uu) >> 2;                                                     \
        int mb = m & 31;                                                       \
        int jl = ((mb >> 3) << 2) + (mb & 3) + ((mb >> 2) & 1) * 16;           \
        int prow = (m & ~31) + jl;                                             \
        int phys = ((prow >> 1) + ((uu) & 3)) & 3;                             \
        *(uint4*)(&KsB[(buf_) * 4096 + prow * 32 + phys * 8]) = reg;           \
    }
#define WRITECH(buf)                                                           \
    {                                                                          \
        const int buf_ = (buf);                                                \
        KWR(t, pk_r0)                                                          \
        KWR(t + 256, pk_r1)                                                    \
        *(uint4*)(&VsB[buf_ * (32 * VSTR) + (t >> 4) * VSTR + (t & 15) * 8]) = pv_r0; \
        *(uint4*)(&VsB[buf_ * (32 * VSTR) + ((t + 256) >> 4) * VSTR + (t & 15) * 8]) = pv_r1; \
    }
    LOADCH(0)                                          // flies under phase A
    // ---- phase A: q[n][d], n in [n0,n0+32), d in [0,32); Qs stride 40
    bf16* Qs = (bf16*)smem + w * 1280;                 // wave-private 32n x 40
    bf16x8 bq0, bq1;
    {
        const bf16* Aw = Wq_bf + (size_t)(h * 32 + lr) * 256 + lg * 8;     // rows d
        const bf16* Bx = xT + (size_t)(b * 4096 + n0 + lr) * 256 + lg * 8; // rows n
        f32x4 aq[2][2] = {};
#pragma unroll
        for (int kk = 0; kk < 8; kk++) {
            bf16x8 a0 = *(const bf16x8*)(Aw + kk * 32);
            bf16x8 a1 = *(const bf16x8*)(Aw + 16 * 256 + kk * 32);
            bf16x8 b0 = *(const bf16x8*)(Bx + kk * 32);
            bf16x8 b1 = *(const bf16x8*)(Bx + 16 * 256 + kk * 32);
            aq[0][0] = MFMA16(a0, b0, aq[0][0], 0, 0, 0);
            aq[0][1] = MFMA16(a0, b1, aq[0][1], 0, 0, 0);
            aq[1][0] = MFMA16(a1, b0, aq[1][0], 0, 0, 0);
            aq[1][1] = MFMA16(a1, b1, aq[1][1], 0, 0, 0);
        }
        // D[row d = i*16+lg*4+r][col n = j*16+lr] -> Qs[n*40 + d], packed b64
#pragma unroll
        for (int i = 0; i < 2; i++)
#pragma unroll
            for (int j = 0; j < 2; j++) {
                bf16x4 pk;
#pragma unroll
                for (int r = 0; r < 4; r++) pk[r] = (bf16)aq[i][j][r];
                *(bf16x4*)(Qs + (j * 16 + lr) * 40 + i * 16 + lg * 4) = pk;
            }
        // same-wave readback (b64 pairs; bank-coprime stride)
        bf16x4 a0 = *(const bf16x4*)(Qs + lr * 40 + lg * 8);
        bf16x4 a1 = *(const bf16x4*)(Qs + lr * 40 + lg * 8 + 4);
        bf16x4 b0 = *(const bf16x4*)(Qs + (16 + lr) * 40 + lg * 8);
        bf16x4 b1 = *(const bf16x4*)(Qs + (16 + lr) * 40 + lg * 8 + 4);
#pragma unroll
        for (int e = 0; e < 4; e++) {
            bq0[e] = a0[e]; bq0[4 + e] = a1[e];
            bq1[e] = b0[e]; bq1[4 + e] = b1[e];
        }
    }
    __syncthreads();               // all waves done with Qs before staging clobbers
    WRITECH(0)                     // vmcnt-gated; window = phase A
    LOADCH(1)
    __syncthreads();               // buf0 visible
    f32x4 accO[2][2] = {};         // [q-half][d-tile]: col d = lr, row n = lg*4+r
    f32x4 accS[2] = {};            // row sums (ones-B MFMA): same row layout
    const f16x8 ones8 = {(_Float16)1.f, (_Float16)1.f, (_Float16)1.f, (_Float16)1.f,
                         (_Float16)1.f, (_Float16)1.f, (_Float16)1.f, (_Float16)1.f};
    const f32x4 zs = {-SOFTMAX_SHIFT, -SOFTMAX_SHIFT, -SOFTMAX_SHIFT, -SOFTMAX_SHIFT};
    const int koff = (((lr >> 1) + lg) & 3) * 8;       // read-side swizzle (const/lane)
    for (int ch = 0; ch < 8; ch++) {
        const bf16* Kc = KsB + (ch & 1) * 4096;
        const _Float16* Vc = VsB + (ch & 1) * (32 * VSTR);
        __builtin_amdgcn_s_setprio(1);
#pragma unroll
        for (int kb = 0; kb < 4; kb++) {               // 32-kv block
            // shared K/V ds_reads for both q-halves
            bf16x8 ak0 = *(const bf16x8*)(Kc + (kb * 32 + lr) * 32 + koff);
            bf16x8 ak1 = *(const bf16x8*)(Kc + (kb * 32 + 16 + lr) * 32 + koff);
            f16x8 v0 = *(const f16x8*)(Vc + lr * VSTR + kb * 32 + lg * 8);
            f16x8 v1 = *(const f16x8*)(Vc + (16 + lr) * VSTR + kb * 32 + lg * 8);
            // ---- q-half 0
            {
                f32x4 s0 = MFMA16(ak0, bq0, zs, 0, 0, 0);  // col q=lr
                f32x4 s1 = MFMA16(ak1, bq0, zs, 0, 0, 0);
                f16x8 pa;
                fp16x2_raw c01 = __builtin_amdgcn_cvt_pkrtz(
                    __builtin_amdgcn_exp2f(s0[0]), __builtin_amdgcn_exp2f(s0[1]));
                fp16x2_raw c23 = __builtin_amdgcn_cvt_pkrtz(
                    __builtin_amdgcn_exp2f(s0[2]), __builtin_amdgcn_exp2f(s0[3]));
                fp16x2_raw c45 = __builtin_amdgcn_cvt_pkrtz(
                    __builtin_amdgcn_exp2f(s1[0]), __builtin_amdgcn_exp2f(s1[1]));
                fp16x2_raw c67 = __builtin_amdgcn_cvt_pkrtz(
                    __builtin_amdgcn_exp2f(s1[2]), __builtin_amdgcn_exp2f(s1[3]));
                pa[0] = c01[0]; pa[1] = c01[1]; pa[2] = c23[0]; pa[3] = c23[1];
                pa[4] = c45[0]; pa[5] = c45[1]; pa[6] = c67[0]; pa[7] = c67[1];
                accO[0][0] = MFMA16H32(pa, v0, accO[0][0], 0, 0, 0);
                accO[0][1] = MFMA16H32(pa, v1, accO[0][1], 0, 0, 0);
                accS[0]    = MFMA16H32(pa, ones8, accS[0], 0, 0, 0);
            }
            // ---- q-half 1
            {
                f32x4 s0 = MFMA16(ak0, bq1, zs, 0, 0, 0);
                f32x4 s1 = MFMA16(ak1, bq1, zs, 0, 0, 0);
                f16x8 pa;
                fp16x2_raw c01 = __builtin_amdgcn_cvt_pkrtz(
                    __builtin_amdgcn_exp2f(s0[0]), __builtin_amdgcn_exp2f(s0[1]));
                fp16x2_raw c23 = __builtin_amdgcn_cvt_pkrtz(
                    __builtin_amdgcn_exp2f(s0[2]), __builtin_amdgcn_exp2f(s0[3]));
                fp16x2_raw c45 = __builtin_amdgcn_cvt_pkrtz(
                    __builtin_amdgcn_exp2f(s1[0]), __builtin_amdgcn_exp2f(s1[1]));
                fp16x2_raw c67 = __builtin_amdgcn_cvt_pkrtz(
                    __builtin_amdgcn_exp2f(s1[2]), __builtin_amdgcn_exp2f(s1[3]));
                pa[0] = c01[0]; pa[1] = c01[1]; pa[2] = c23[0]; pa[3] = c23[1];
                pa[4] = c45[0]; pa[5] = c45[1]; pa[6] = c67[0]; pa[7] = c67[1];
                accO[1][0] = MFMA16H32(pa, v0, accO[1][0], 0, 0, 0);
                accO[1][1] = MFMA16H32(pa, v1, accO[1][1], 0, 0, 0);
                accS[1]    = MFMA16H32(pa, ones8, accS[1], 0, 0, 0);
            }
        }
        __builtin_amdgcn_s_setprio(0);
        if (ch < 7) {
            WRITECH((ch + 1) & 1)                      // vmcnt-gated, sunk after compute
            if (ch < 6) LOADCH(ch + 2)                 // in flight across next barrier
            __syncthreads();
        }
    }
#undef LOADCH
#undef KWR
#undef WRITECH
    // accS[hq][r] = rowsum(n = hq*16+lg*4+r), duplicated across cols
#pragma unroll
    for (int hq = 0; hq < 2; hq++) {
        float inv[4];
#pragma unroll
        for (int r = 0; r < 4; r++) inv[r] = 1.0f / accS[hq][r];
#pragma unroll
        for (int dt = 0; dt < 2; dt++) {
            int c = h * 32 + dt * 16 + lr;             // accO col = d = lr
            float* op = out + (size_t)(b * 256 + c) * 4096 + n0 + hq * 16 + lg * 4;
            f32x4 o;
#pragma unroll
            for (int r = 0; r < 4; r++) o[r] = accO[hq][dt][r] * inv[r];
            *(f32x4*)op = o;
        }
    }
}

// ---------------------------------------------------------------- launcher
extern "C" void kernel_launch(void* const* d_in, const int* in_sizes, int n_in,
                              void* d_out, int out_size, void* d_ws, size_t ws_size,
                              hipStream_t stream) {
    const float* x    = (const float*)d_in[0];
    const float* Wq   = (const float*)d_in[1];
    const float* Wk   = (const float*)d_in[2];
    const float* Wv   = (const float*)d_in[3];
    const float* relh = (const float*)d_in[4];
    const float* relw = (const float*)d_in[5];
    float* out = (float*)d_out;
    char* ws = (char*)d_ws;

    bf16*      xT     = (bf16*)(ws);                                  // 8 MiB
    bf16*      kposT  = (bf16*)(ws + (8u << 20));                     // 2 MiB
    _Float16*  v_td   = (_Float16*)(ws + (10u << 20));                // 2 MiB
    bf16*      Wq_bf  = (bf16*)(ws + (12u << 20));                    // 128 KiB
    bf16*      Wkv_bf = (bf16*)(ws + (12u << 20) + (256u << 10));     // 1 MiB

    k_prep_w <<<192,            256, 0, stream>>>(Wq, Wk, Wv, Wq_bf, Wkv_bf);
    k_xT     <<<dim3(64, 4, 4), 256, 0, stream>>>(x, xT);
    k_gemm_kv<<<dim3(32, 4, 4), 256, 0, stream>>>(xT, Wkv_bf, relh, relw, kposT, v_td);
    k_attn   <<<dim3(32, 8, 4), 256, 0, stream>>>(xT, Wq_bf, kposT, v_td, out);
}